// Round 8
// baseline (6912.370 us; speedup 1.0000x reference)
//
#include <hip/hip_runtime.h>
#include <hip/hip_bf16.h>
#include <cstdio>

// Original stub symbol kept verbatim (in case the harness looks it up).
__global__ void PoseVideoCNNRNN_87497073754264_kernel() {}

__device__ __forceinline__ float pv_sigm(float x){ return 1.0f/(1.0f + __expf(-x)); }
__device__ __forceinline__ float pv_tanh(float x){ float e = __expf(2.0f*x); return 1.0f - 2.0f/(e + 1.0f); }

__device__ __forceinline__ unsigned short pv_f2b(float x){
  union { float f; unsigned u; } c; c.f = x;
  unsigned r = (c.u + 0x7fffu + ((c.u >> 16) & 1u)) >> 16;
  return (unsigned short)r;
}
__device__ __forceinline__ float pv_b2f(unsigned short v){
  union { unsigned u; float f; } c; c.u = ((unsigned)v) << 16;
  return c.f;
}

// ---------------------------------------------------------------------------
// pv_prep_lstm: transpose lstm_Whh (512x128) -> whhT[k][g] (128x512)
// ---------------------------------------------------------------------------
__global__ void pv_prep_lstm(const float* Whh, float* whhT){
  int idx = blockIdx.x*256 + threadIdx.x;
  if (idx < 65536) {
    int k = idx >> 9;
    int g = idx & 511;
    whhT[idx] = Whh[g*128 + k];
  }
}

// ---------------------------------------------------------------------------
// pv_prep_gru: pack gru_Whh (783x261) into bf16 pairs, rows padded to 132
// pairs; layout [row][kp].
// ---------------------------------------------------------------------------
__global__ void pv_prep_gru(const float* Whh, unsigned* whhPb){
  int idx = blockIdx.x*256 + threadIdx.x;   // < 783*132 = 103356
  if (idx >= 103356) return;
  int r = idx / 132;
  int kp = idx - r*132;
  int k = kp*2;
  float w0 = (k < 261) ? Whh[r*261 + k] : 0.0f;
  float w1 = (k + 1 < 261) ? Whh[r*261 + k + 1] : 0.0f;
  whhPb[idx] = ((unsigned)pv_f2b(w1) << 16) | (unsigned)pv_f2b(w0);
}

// ---------------------------------------------------------------------------
// pv_gemm: xg = leaky(pose @ projW^T + projb, 0.1) @ lstm_Wih^T + bih + bhh
// M=12800 (row = b*100+t), N=512, K=4096. fp32 VALU, 128x128 tile, BK=32.
// Output fp32: xg[(t*128+b)*512 + gate]
// ---------------------------------------------------------------------------
__global__ __launch_bounds__(256) void pv_gemm(
    const float* pose, const float* projW, const float* projb,
    const float* Wih, const float* bih, const float* bhh,
    float* xg)
{
  __shared__ float As[32*132];
  __shared__ float Bs[32*132];
  const int tid = threadIdx.x;
  const int m0 = blockIdx.x * 128;
  const int n0 = blockIdx.y * 128;

  const int rl = tid >> 1;
  const int kq = (tid & 1) * 16;
  float p0,p1,p2,p3,p4,p5,p6,p7,p8;
  {
    const float* pr = pose + (m0 + rl) * 9;
    p0=pr[0]; p1=pr[1]; p2=pr[2]; p3=pr[3]; p4=pr[4];
    p5=pr[5]; p6=pr[6]; p7=pr[7]; p8=pr[8];
  }

  const int ty = tid >> 4;
  const int tx = tid & 15;

  float acc[8][8];
  for (int i = 0; i < 8; ++i)
    for (int j = 0; j < 8; ++j) acc[i][j] = 0.0f;

  for (int kk = 0; kk < 128; ++kk) {
    __syncthreads();
    for (int i = 0; i < 4; ++i) {
      int fidx = tid + i*256;
      int nl = fidx >> 3;
      int kf = (fidx & 7) * 4;
      const float* src = Wih + (n0 + nl)*4096 + kk*32 + kf;
      Bs[(kf+0)*132 + nl] = src[0];
      Bs[(kf+1)*132 + nl] = src[1];
      Bs[(kf+2)*132 + nl] = src[2];
      Bs[(kf+3)*132 + nl] = src[3];
    }
    {
      const float* wbase = projW + (kk*32 + kq)*9;
      const float* bbase = projb + kk*32 + kq;
      for (int u = 0; u < 16; ++u) {
        const float* wr = wbase + u*9;
        float s = bbase[u] + p0*wr[0] + p1*wr[1] + p2*wr[2] + p3*wr[3]
                + p4*wr[4] + p5*wr[5] + p6*wr[6] + p7*wr[7] + p8*wr[8];
        s = fmaxf(s, 0.1f*s);
        As[(kq+u)*132 + rl] = s;
      }
    }
    __syncthreads();
    for (int k = 0; k < 32; ++k) {
      const float* arow = As + k*132 + ty*8;
      const float* brow = Bs + k*132 + tx*8;
      float a[8], b[8];
      for (int e = 0; e < 8; ++e) { a[e] = arow[e]; b[e] = brow[e]; }
      for (int i = 0; i < 8; ++i)
        for (int j = 0; j < 8; ++j) acc[i][j] += a[i]*b[j];
    }
  }
  for (int i = 0; i < 8; ++i) {
    int row = m0 + ty*8 + i;
    int bb = row / 100;
    int tt = row - bb*100;
    float* orow = xg + (tt*128 + bb)*512 + n0 + tx*8;
    for (int j = 0; j < 8; ++j) {
      int col = n0 + tx*8 + j;
      orow[j] = acc[i][j] + bih[col] + bhh[col];
    }
  }
}

// ---------------------------------------------------------------------------
// pv_lstm: 64 WGs x 256 threads, 2 batches/WG.
// ---------------------------------------------------------------------------
__global__ __launch_bounds__(256) void pv_lstm(
    const float* xg, const float* whhT, float* hT)
{
  __shared__ float hs[2*128];
  __shared__ float Ds[2*512];
  const int tid = threadIdx.x;
  const int m0 = blockIdx.x * 2;
  const int g0 = tid, g1 = tid + 256;
  const int um = tid >> 7, uj = tid & 127;
  hs[tid] = 0.0f;
  float creg = 0.0f;
  __syncthreads();

  for (int t = 0; t < 100; ++t) {
    float d00=0.f, d01=0.f, d10=0.f, d11=0.f;
    for (int kb = 0; kb < 32; ++kb) {
      float ha0 = hs[4*kb+0], ha1 = hs[4*kb+1], ha2 = hs[4*kb+2], ha3 = hs[4*kb+3];
      float hb0 = hs[128+4*kb+0], hb1 = hs[128+4*kb+1], hb2 = hs[128+4*kb+2], hb3 = hs[128+4*kb+3];
      const float* w0 = whhT + (kb*4)*512 + g0;
      const float* w1 = w0 + 256;
      float w;
      w = w0[0];    d00 += w*ha0; d01 += w*hb0;
      w = w0[512];  d00 += w*ha1; d01 += w*hb1;
      w = w0[1024]; d00 += w*ha2; d01 += w*hb2;
      w = w0[1536]; d00 += w*ha3; d01 += w*hb3;
      w = w1[0];    d10 += w*ha0; d11 += w*hb0;
      w = w1[512];  d10 += w*ha1; d11 += w*hb1;
      w = w1[1024]; d10 += w*ha2; d11 += w*hb2;
      w = w1[1536]; d10 += w*ha3; d11 += w*hb3;
    }
    const float* xb = xg + (t*128 + m0)*512;
    d00 += xb[g0];
    d10 += xb[g1];
    d01 += xb[512 + g0];
    d11 += xb[512 + g1];
    Ds[g0] = d00; Ds[g1] = d10; Ds[512 + g0] = d01; Ds[512 + g1] = d11;
    __syncthreads();
    {
      float gi = Ds[um*512 + uj];
      float gf = Ds[um*512 + 128 + uj];
      float gg = Ds[um*512 + 256 + uj];
      float go = Ds[um*512 + 384 + uj];
      float c = pv_sigm(gf)*creg + pv_sigm(gi)*pv_tanh(gg);
      creg = c;
      float h = pv_sigm(go)*pv_tanh(c);
      hs[um*128 + uj] = h;
      if (t == 99) hT[(m0 + um)*128 + uj] = h;
    }
    __syncthreads();
  }
}

// ---------------------------------------------------------------------------
// pv_head: mu, logvar (-> d_out FP32), embedding, x = fcin(emb)
// ---------------------------------------------------------------------------
__global__ __launch_bounds__(64) void pv_head(
    const float* hT, const float* eps,
    const float* muW, const float* mub,
    const float* lvW, const float* lvb,
    const float* fcW, const float* fcb,
    float* xvec, float* out)
{
  __shared__ float hrow[128];
  __shared__ float emb[64];
  const int b = blockIdx.x, j = threadIdx.x;
  hrow[j] = hT[b*128 + j];
  hrow[j + 64] = hT[b*128 + 64 + j];
  __syncthreads();
  float sm = mub[j], sl = lvb[j];
  for (int k = 0; k < 128; ++k) {
    sm += hrow[k]*muW[j*128 + k];
    sl += hrow[k]*lvW[j*128 + k];
  }
  float mu = fmaxf(sm, 0.1f*sm);
  float lv = fmaxf(sl, 0.1f*sl);
  lv = fminf(fmaxf(lv, -10.0f), 10.0f);
  float em = mu + eps[b*64 + j]*__expf(0.5f*lv);
  emb[j] = em;
  out[115200 + b*64 + j] = mu;     // FP32 output
  out[123392 + b*64 + j] = lv;     // FP32 output
  __syncthreads();
  for (int c4 = 0; c4 < 4; ++c4) {
    int c = c4*64 + j;
    float s = fcb[c];
    for (int k = 0; k < 64; ++k) s += emb[k]*fcW[c*64 + k];
    xvec[b*256 + c] = s;
  }
}

// ---------------------------------------------------------------------------
// pv_gxbase: gxb[b][g] = x[b]@Wih[g][0:256] + bih[g] + (g<522 ? bhh[g] : 0)
// ---------------------------------------------------------------------------
__global__ __launch_bounds__(256) void pv_gxbase(
    const float* xvec, const float* Wih,
    const float* bih, const float* bhh, float* gxb)
{
  __shared__ float xs[8*256];
  const int tid = threadIdx.x;
  const int bg = blockIdx.x;
  const int gg = blockIdx.y;
  for (int i = tid; i < 2048; i += 256) xs[i] = xvec[bg*2048 + i];
  __syncthreads();
  const int g = gg*256 + tid;
  if (g >= 783) return;
  float bias = bih[g] + ((g < 522) ? bhh[g] : 0.0f);
  float a0=bias,a1=bias,a2=bias,a3=bias,a4=bias,a5=bias,a6=bias,a7=bias;
  const float* wr = Wih + g*261;
  for (int k = 0; k < 256; ++k) {
    float w = wr[k];
    a0 += xs[0*256 + k]*w; a1 += xs[1*256 + k]*w;
    a2 += xs[2*256 + k]*w; a3 += xs[3*256 + k]*w;
    a4 += xs[4*256 + k]*w; a5 += xs[5*256 + k]*w;
    a6 += xs[6*256 + k]*w; a7 += xs[7*256 + k]*w;
  }
  gxb[(bg*8 + 0)*783 + g] = a0; gxb[(bg*8 + 1)*783 + g] = a1;
  gxb[(bg*8 + 2)*783 + g] = a2; gxb[(bg*8 + 3)*783 + g] = a3;
  gxb[(bg*8 + 4)*783 + g] = a4; gxb[(bg*8 + 5)*783 + g] = a5;
  gxb[(bg*8 + 6)*783 + g] = a6; gxb[(bg*8 + 7)*783 + g] = a7;
}

// ---------------------------------------------------------------------------
// pv_gru_frames: GRU recurrence fused with the per-step joint head.
// Frames written to d_out as FP32 at (b*900 + t*9 + oc).
// ---------------------------------------------------------------------------
__global__ __launch_bounds__(256) void pv_gru_frames(
    const float* gxb, const unsigned* whhPb, const float* Wih,
    const float* bhh, const float* noise,
    const float* W1, const float* b1, const float* W2, const float* b2,
    float* out)
{
  __shared__ float hs[2*264];
  __shared__ float Dsh[783*2];
  __shared__ float wrt[783*5];
  __shared__ unsigned short w1b[64*261];
  __shared__ float w2s[576];
  __shared__ float f1s[2*64];
  const int tid = threadIdx.x;
  const int m0 = blockIdx.x * 2;

  for (int i = tid; i < 2*264; i += 256) hs[i] = 0.0f;
  for (int i = tid; i < 3915; i += 256) {
    int g = i/5;
    wrt[i] = Wih[g*261 + 256 + (i - g*5)];
  }
  for (int i = tid; i < 16704; i += 256) w1b[i] = pv_f2b(W1[i]);
  for (int i = tid; i < 576; i += 256) w2s[i] = W2[i];
  float hreg[7];
  for (int e = 0; e < 7; ++e) hreg[e] = 0.0f;
  __syncthreads();

  for (int t = 0; t < 100; ++t) {
    {
      float a00=0.f,a01=0.f,a10=0.f,a11=0.f,a20=0.f,a21=0.f;
      const unsigned* w0 = whhPb + tid*132;
      const unsigned* w1 = whhPb + (tid+256)*132;
      const unsigned* w2 = whhPb + (tid+512)*132;
      for (int kp = 0; kp < 131; ++kp) {
        float h0a = hs[2*kp], h0b = hs[2*kp+1];
        float h1a = hs[264+2*kp], h1b = hs[264+2*kp+1];
        unsigned u; float wl, wh;
        u = w0[kp]; wl = pv_b2f((unsigned short)(u & 0xffffu)); wh = pv_b2f((unsigned short)(u >> 16));
        a00 += wl*h0a + wh*h0b; a01 += wl*h1a + wh*h1b;
        u = w1[kp]; wl = pv_b2f((unsigned short)(u & 0xffffu)); wh = pv_b2f((unsigned short)(u >> 16));
        a10 += wl*h0a + wh*h0b; a11 += wl*h1a + wh*h1b;
        u = w2[kp]; wl = pv_b2f((unsigned short)(u & 0xffffu)); wh = pv_b2f((unsigned short)(u >> 16));
        a20 += wl*h0a + wh*h0b; a21 += wl*h1a + wh*h1b;
      }
      Dsh[tid*2 + 0] = a00;         Dsh[tid*2 + 1] = a01;
      Dsh[(tid+256)*2 + 0] = a10;   Dsh[(tid+256)*2 + 1] = a11;
      Dsh[(tid+512)*2 + 0] = a20;   Dsh[(tid+512)*2 + 1] = a21;
      if (tid < 15) {
        int r3 = 768 + tid;
        float a30 = 0.f, a31 = 0.f;
        const unsigned* w3 = whhPb + r3*132;
        for (int kp = 0; kp < 131; ++kp) {
          float h0a = hs[2*kp], h0b = hs[2*kp+1];
          float h1a = hs[264+2*kp], h1b = hs[264+2*kp+1];
          unsigned u = w3[kp];
          float wl = pv_b2f((unsigned short)(u & 0xffffu));
          float wh = pv_b2f((unsigned short)(u >> 16));
          a30 += wl*h0a + wh*h0b; a31 += wl*h1a + wh*h1b;
        }
        Dsh[r3*2 + 0] = a30;        Dsh[r3*2 + 1] = a31;
      }
    }
    __syncthreads();
    const float tv = (float)t * (1.0f/99.0f);
    for (int e = 0; e < 7; ++e) {
      int el = tid + e*256;
      if (el < 1566) {
        int j = el >> 1, m = el & 1;
        const float* nep = noise + (t*128 + m0 + m)*4;
        float n0 = nep[0]*0.1f, n1 = nep[1]*0.1f, n2 = nep[2]*0.1f, n3 = nep[3]*0.1f;
        const float* wr_ = wrt + j*5;
        const float* wz_ = wrt + (261 + j)*5;
        const float* wn_ = wrt + (522 + j)*5;
        const float* gb = gxb + (m0 + m)*783;
        float rterm = n0*wr_[0] + n1*wr_[1] + n2*wr_[2] + n3*wr_[3] + tv*wr_[4];
        float zterm = n0*wz_[0] + n1*wz_[1] + n2*wz_[2] + n3*wz_[3] + tv*wz_[4];
        float nterm = n0*wn_[0] + n1*wn_[1] + n2*wn_[2] + n3*wn_[3] + tv*wn_[4];
        float r_ = pv_sigm(Dsh[j*2 + m] + gb[j] + rterm);
        float z_ = pv_sigm(Dsh[(261 + j)*2 + m] + gb[261 + j] + zterm);
        float n_ = pv_tanh(gb[522 + j] + nterm + r_*(Dsh[(522 + j)*2 + m] + bhh[522 + j]));
        float h = (1.0f - z_)*n_ + z_*hreg[e];
        hreg[e] = h;
        hs[m*264 + j] = h;
      }
    }
    __syncthreads();
    if (tid < 128) {
      int m = tid >> 6, c = tid & 63;
      float s = b1[c];
      const unsigned short* wc = w1b + c*261;
      const float* hm = hs + m*264;
      for (int k = 0; k < 261; ++k) s += pv_b2f(wc[k]) * hm[k];
      f1s[m*64 + c] = fmaxf(s, 0.2f*s);
    }
    __syncthreads();
    if (tid < 18) {
      int m = tid / 9, oc = tid - (tid/9)*9;
      float s = b2[oc];
      const float* fm = f1s + m*64;
      const float* wo = w2s + oc*64;
      for (int k = 0; k < 64; ++k) s += fm[k]*wo[k];
      out[(m0 + m)*900 + t*9 + oc] = pv_sigm(s);   // FP32 output
    }
  }
}

// ---------------------------------------------------------------------------
extern "C" __attribute__((visibility("default")))
void kernel_launch(void* const* d_in, const int* in_sizes, int n_in,
                   void* d_out, int out_size, void* d_ws, size_t ws_size,
                   hipStream_t stream)
{
  (void)in_sizes; (void)n_in;

  // sentinel (fp32 buffer): fully overwritten by a working pipeline
  hipMemsetAsync(d_out, 0x40, (size_t)out_size * 4, stream);

  const float* input_data = (const float*)d_in[0];
  const float* eps        = (const float*)d_in[1];
  const float* noise_eps  = (const float*)d_in[2];
  const float* proj_W     = (const float*)d_in[3];
  const float* proj_b     = (const float*)d_in[4];
  const float* lstm_Wih   = (const float*)d_in[5];
  const float* lstm_Whh   = (const float*)d_in[6];
  const float* lstm_bih   = (const float*)d_in[7];
  const float* lstm_bhh   = (const float*)d_in[8];
  const float* mu_W       = (const float*)d_in[9];
  const float* mu_b       = (const float*)d_in[10];
  const float* lv_W       = (const float*)d_in[11];
  const float* lv_b       = (const float*)d_in[12];
  const float* fcin_W     = (const float*)d_in[13];
  const float* fcin_b     = (const float*)d_in[14];
  const float* gru_Wih    = (const float*)d_in[15];
  const float* gru_Whh    = (const float*)d_in[16];
  const float* gru_bih    = (const float*)d_in[17];
  const float* gru_bhh    = (const float*)d_in[18];
  const float* jf_W1      = (const float*)d_in[19];
  const float* jf_b1      = (const float*)d_in[20];
  const float* jf_W2      = (const float*)d_in[21];
  const float* jf_b2      = (const float*)d_in[22];

  char* w = (char*)d_ws;
  float*    xg    = (float*)(w);                    // 26,214,400 B
  float*    whhT  = (float*)(w + 26214400);         //    262,144 B
  unsigned* whhPb = (unsigned*)(w + 26476544);      //    413,424 B
  float*    hT    = (float*)(w + 26889968);         //     65,536 B
  float*    xvec  = (float*)(w + 26955504);         //    131,072 B
  float*    gxb   = (float*)(w + 27086576);         //    400,896 B (end 27.5 MB)
  float*    outf  = (float*)d_out;                  // FP32: 131584 elements

  pv_prep_lstm<<<256, 256, 0, stream>>>(lstm_Whh, whhT);
  pv_prep_gru<<<404, 256, 0, stream>>>(gru_Whh, whhPb);
  pv_gemm<<<dim3(100, 4), 256, 0, stream>>>(input_data, proj_W, proj_b,
                                            lstm_Wih, lstm_bih, lstm_bhh, xg);
  pv_lstm<<<64, 256, 0, stream>>>(xg, whhT, hT);
  pv_head<<<128, 64, 0, stream>>>(hT, eps, mu_W, mu_b, lv_W, lv_b,
                                  fcin_W, fcin_b, xvec, outf);
  pv_gxbase<<<dim3(16, 4), 256, 0, stream>>>(xvec, gru_Wih, gru_bih, gru_bhh, gxb);
  pv_gru_frames<<<64, 256, 0, stream>>>(gxb, whhPb, gru_Wih, gru_bhh, noise_eps,
                                        jf_W1, jf_b1, jf_W2, jf_b2, outf);

  // capture-guarded diagnostic: confirm fp32 frame values land in d_out.
  {
    hipStreamCaptureStatus cs = hipStreamCaptureStatusNone;
    hipStreamIsCapturing(stream, &cs);
    if (cs == hipStreamCaptureStatusNone) {
      float hbuf[4] = {-1.f,-1.f,-1.f,-1.f};
      hipError_t es = hipStreamSynchronize(stream);
      hipError_t ec = hipMemcpy(hbuf, d_out, 16, hipMemcpyDeviceToHost);
      float tail[2] = {-1.f,-1.f};
      hipMemcpy(tail, (const char*)d_out + (size_t)115199*4, 8, hipMemcpyDeviceToHost);
      fprintf(stderr, "PV8 OUT f32 %.6f %.6f %.6f %.6f | last_frame=%.6f mu0=%.6f es=%d ec=%d\n",
              hbuf[0], hbuf[1], hbuf[2], hbuf[3], tail[0], tail[1], (int)es, (int)ec);
      fflush(stderr);
    }
  }
}

// Round 9
// 2605.888 us; speedup vs baseline: 2.6526x; 2.6526x over previous
//
#include <hip/hip_runtime.h>
#include <hip/hip_bf16.h>

typedef float f32x4 __attribute__((ext_vector_type(4)));
typedef short s16x8 __attribute__((ext_vector_type(8)));

__device__ __forceinline__ float pv_sigm(float x){ return 1.0f/(1.0f + __expf(-x)); }
__device__ __forceinline__ float pv_tanh(float x){ float e = __expf(2.0f*x); return 1.0f - 2.0f/(e + 1.0f); }

__device__ __forceinline__ unsigned short pv_f2b(float x){
  union { float f; unsigned u; } c; c.f = x;
  unsigned r = (c.u + 0x7fffu + ((c.u >> 16) & 1u)) >> 16;
  return (unsigned short)r;
}
__device__ __forceinline__ float pv_b2f(unsigned short v){
  union { unsigned u; float f; } c; c.u = ((unsigned)v) << 16;
  return c.f;
}
__device__ __forceinline__ unsigned pv_pack2(float a, float b){
  return ((unsigned)pv_f2b(b) << 16) | (unsigned)pv_f2b(a);
}
__device__ __forceinline__ float pv_lo(unsigned u){
  union { unsigned u; float f; } c; c.u = u << 16; return c.f;
}
__device__ __forceinline__ float pv_hi(unsigned u){
  union { unsigned u; float f; } c; c.u = u & 0xffff0000u; return c.f;
}

// ---------------------------------------------------------------------------
// pv_prep_lstm: transpose lstm_Whh (512x128) -> whhT[k][g] (128x512)
// ---------------------------------------------------------------------------
__global__ void pv_prep_lstm(const float* Whh, float* whhT){
  int idx = blockIdx.x*256 + threadIdx.x;
  if (idx < 65536) {
    int k = idx >> 9;
    int g = idx & 511;
    whhT[idx] = Whh[g*128 + k];
  }
}

// ---------------------------------------------------------------------------
// pv_prep_gru: pack gru_Whh (783x261) into bf16 pairs, layout [kp][row]
// (kp = k/2 in 0..130, row padded to 784) -> coalesced streaming in pv_gru.
// ---------------------------------------------------------------------------
__global__ void pv_prep_gru(const float* Whh, unsigned* whhPb){
  int idx = blockIdx.x*256 + threadIdx.x;   // < 131*784 = 102704
  if (idx >= 131*784) return;
  int kp = idx / 784;
  int r  = idx - kp*784;
  unsigned v = 0u;
  if (r < 783) {
    int k = kp*2;
    float w0 = Whh[r*261 + k];
    float w1 = (k + 1 < 261) ? Whh[r*261 + k + 1] : 0.0f;
    v = pv_pack2(w0, w1);
  }
  whhPb[idx] = v;
}

// ---------------------------------------------------------------------------
// pv_gemm: xg = leaky(pose @ projW^T + projb, 0.1) @ lstm_Wih^T + bih + bhh
// M=12800 (row = b*100+t), N=512, K=4096.  bf16 MFMA 16x16x32, 128x128 tile,
// BK=32, 256 threads (4 waves, each 64x64).  A generated on the fly.
// LDS rows stride 48 bf16 (96 B) -> ds_read_b128 stays 16B-aligned.
// Output fp32: xg[(t*128+b)*512 + gate]
// ---------------------------------------------------------------------------
__global__ __launch_bounds__(256) void pv_gemm(
    const float* pose, const float* projW, const float* projb,
    const float* Wih, const float* bih, const float* bhh,
    float* xg)
{
  __shared__ __align__(16) unsigned As[128*24];   // bf16 pairs, row stride 24 u32
  __shared__ __align__(16) unsigned Bs[128*24];
  __shared__ float Ws[320];                       // projW chunk (32x9) + projb (32)

  const int tid = threadIdx.x;
  const int m0 = blockIdx.x * 128;
  const int n0 = blockIdx.y * 128;

  const int rl = tid >> 1;            // A-gen row
  const int kh = tid & 1;             // A-gen k-half
  float p0,p1,p2,p3,p4,p5,p6,p7,p8;
  {
    const float* pr = pose + (m0 + rl) * 9;
    p0=pr[0]; p1=pr[1]; p2=pr[2]; p3=pr[3]; p4=pr[4];
    p5=pr[5]; p6=pr[6]; p7=pr[7]; p8=pr[8];
  }

  const int wave = tid >> 6;
  const int lane = tid & 63;
  const int wm = wave >> 1, wn = wave & 1;
  const int l16 = lane & 15, quad = lane >> 4;

  f32x4 acc[4][4];
  #pragma unroll
  for (int i = 0; i < 4; ++i)
    #pragma unroll
    for (int j = 0; j < 4; ++j) acc[i][j] = (f32x4){0.f,0.f,0.f,0.f};

  for (int kk = 0; kk < 128; ++kk) {
    __syncthreads();   // protect As/Bs/Ws against previous iteration's readers
    for (int idx = tid; idx < 320; idx += 256)
      Ws[idx] = (idx < 288) ? projW[kk*288 + idx] : projb[kk*32 + (idx - 288)];
    #pragma unroll
    for (int i = 0; i < 8; ++i) {
      int q = tid + i*256;
      int nl = q >> 4;
      int kp = q & 15;
      const float* src = Wih + (n0 + nl)*4096 + kk*32 + kp*2;
      Bs[nl*24 + kp] = pv_pack2(src[0], src[1]);
    }
    __syncthreads();
    {
      const int kbase = kh*16;
      const float* wbase = Ws + kbase*9;
      float av[16];
      #pragma unroll
      for (int u = 0; u < 16; ++u) {
        const float* wr = wbase + u*9;
        float s = Ws[288 + kbase + u]
                + p0*wr[0] + p1*wr[1] + p2*wr[2] + p3*wr[3] + p4*wr[4]
                + p5*wr[5] + p6*wr[6] + p7*wr[7] + p8*wr[8];
        av[u] = fmaxf(s, 0.1f*s);
      }
      #pragma unroll
      for (int q = 0; q < 8; ++q)
        As[rl*24 + kh*8 + q] = pv_pack2(av[2*q], av[2*q+1]);
    }
    __syncthreads();
    const unsigned short* As16 = (const unsigned short*)As;
    const unsigned short* Bs16 = (const unsigned short*)Bs;
    s16x8 af[4], bfv[4];
    #pragma unroll
    for (int i = 0; i < 4; ++i)
      af[i] = *(const s16x8*)(As16 + (wm*64 + i*16 + l16)*48 + quad*8);
    #pragma unroll
    for (int j = 0; j < 4; ++j)
      bfv[j] = *(const s16x8*)(Bs16 + (wn*64 + j*16 + l16)*48 + quad*8);
    #pragma unroll
    for (int i = 0; i < 4; ++i)
      #pragma unroll
      for (int j = 0; j < 4; ++j)
        acc[i][j] = __builtin_amdgcn_mfma_f32_16x16x32_bf16(af[i], bfv[j], acc[i][j], 0, 0, 0);
  }
  // epilogue: + (bih+bhh), scatter to (t,b,gate).  C/D map: col=lane&15,
  // row=quad*4+reg  [verified m89/m91]
  #pragma unroll
  for (int j = 0; j < 4; ++j) {
    int col = n0 + wn*64 + j*16 + l16;
    float bsum = bih[col] + bhh[col];
    #pragma unroll
    for (int i = 0; i < 4; ++i) {
      #pragma unroll
      for (int r = 0; r < 4; ++r) {
        int row = m0 + wm*64 + i*16 + quad*4 + r;   // = b*100 + t
        int bb = row / 100;
        int tt = row - bb*100;
        xg[(tt*128 + bb)*512 + col] = acc[i][j][r] + bsum;
      }
    }
  }
}

// ---------------------------------------------------------------------------
// pv_lstm: 64 WGs x 256 threads, 2 batches/WG.  Whh fp32 resident in VGPRs
// (256 regs/thread; launch_bounds(256,1) grants the budget).  h in LDS,
// float4 broadcast reads.
// ---------------------------------------------------------------------------
__global__ __launch_bounds__(256, 1) void pv_lstm(
    const float* xg, const float* whhT, float* hT)
{
  __shared__ __align__(16) float hs[2*128];
  __shared__ float Ds[2*512];
  const int tid = threadIdx.x;
  const int m0 = blockIdx.x * 2;
  const int g0 = tid, g1 = tid + 256;
  const int um = tid >> 7, uj = tid & 127;

  float wv0[128], wv1[128];
  #pragma unroll
  for (int k = 0; k < 128; ++k) wv0[k] = whhT[k*512 + g0];
  #pragma unroll
  for (int k = 0; k < 128; ++k) wv1[k] = whhT[k*512 + g1];

  hs[tid] = 0.0f;
  float creg = 0.0f;
  __syncthreads();

  const f32x4* h40 = (const f32x4*)hs;
  const f32x4* h41 = (const f32x4*)(hs + 128);

  for (int t = 0; t < 100; ++t) {
    float d00=0.f, d01=0.f, d10=0.f, d11=0.f;
    #pragma unroll
    for (int k4 = 0; k4 < 32; ++k4) {
      f32x4 ha = h40[k4];
      f32x4 hb = h41[k4];
      #pragma unroll
      for (int e = 0; e < 4; ++e) {
        float w0 = wv0[k4*4 + e], w1 = wv1[k4*4 + e];
        d00 += w0*ha[e]; d01 += w0*hb[e];
        d10 += w1*ha[e]; d11 += w1*hb[e];
      }
    }
    const float* xb = xg + (t*128 + m0)*512;
    d00 += xb[g0];
    d10 += xb[g1];
    d01 += xb[512 + g0];
    d11 += xb[512 + g1];
    Ds[g0] = d00; Ds[g1] = d10; Ds[512 + g0] = d01; Ds[512 + g1] = d11;
    __syncthreads();
    {
      float gi = Ds[um*512 + uj];
      float gf = Ds[um*512 + 128 + uj];
      float gg = Ds[um*512 + 256 + uj];
      float go = Ds[um*512 + 384 + uj];
      float c = pv_sigm(gf)*creg + pv_sigm(gi)*pv_tanh(gg);
      creg = c;
      float h = pv_sigm(go)*pv_tanh(c);
      hs[um*128 + uj] = h;
      if (t == 99) hT[(m0 + um)*128 + uj] = h;
    }
    __syncthreads();
  }
}

// ---------------------------------------------------------------------------
// pv_head: mu, logvar (-> d_out FP32), embedding, x = fcin(emb)
// ---------------------------------------------------------------------------
__global__ __launch_bounds__(64) void pv_head(
    const float* hT, const float* eps,
    const float* muW, const float* mub,
    const float* lvW, const float* lvb,
    const float* fcW, const float* fcb,
    float* xvec, float* out)
{
  __shared__ float hrow[128];
  __shared__ float emb[64];
  const int b = blockIdx.x, j = threadIdx.x;
  hrow[j] = hT[b*128 + j];
  hrow[j + 64] = hT[b*128 + 64 + j];
  __syncthreads();
  float sm = mub[j], sl = lvb[j];
  for (int k = 0; k < 128; ++k) {
    sm += hrow[k]*muW[j*128 + k];
    sl += hrow[k]*lvW[j*128 + k];
  }
  float mu = fmaxf(sm, 0.1f*sm);
  float lv = fmaxf(sl, 0.1f*sl);
  lv = fminf(fmaxf(lv, -10.0f), 10.0f);
  float em = mu + eps[b*64 + j]*__expf(0.5f*lv);
  emb[j] = em;
  out[115200 + b*64 + j] = mu;
  out[123392 + b*64 + j] = lv;
  __syncthreads();
  for (int c4 = 0; c4 < 4; ++c4) {
    int c = c4*64 + j;
    float s = fcb[c];
    for (int k = 0; k < 64; ++k) s += emb[k]*fcW[c*64 + k];
    xvec[b*256 + c] = s;
  }
}

// ---------------------------------------------------------------------------
// pv_gxbase: gxb[b][g] = x[b]@Wih[g][0:256] + bih[g] + (g<522 ? bhh[g] : 0)
// ---------------------------------------------------------------------------
__global__ __launch_bounds__(256) void pv_gxbase(
    const float* xvec, const float* Wih,
    const float* bih, const float* bhh, float* gxb)
{
  __shared__ float xs[8*256];
  const int tid = threadIdx.x;
  const int bg = blockIdx.x;
  const int gg = blockIdx.y;
  for (int i = tid; i < 2048; i += 256) xs[i] = xvec[bg*2048 + i];
  __syncthreads();
  const int g = gg*256 + tid;
  if (g >= 783) return;
  float bias = bih[g] + ((g < 522) ? bhh[g] : 0.0f);
  float a0=bias,a1=bias,a2=bias,a3=bias,a4=bias,a5=bias,a6=bias,a7=bias;
  const float* wr = Wih + g*261;
  for (int k = 0; k < 256; ++k) {
    float w = wr[k];
    a0 += xs[0*256 + k]*w; a1 += xs[1*256 + k]*w;
    a2 += xs[2*256 + k]*w; a3 += xs[3*256 + k]*w;
    a4 += xs[4*256 + k]*w; a5 += xs[5*256 + k]*w;
    a6 += xs[6*256 + k]*w; a7 += xs[7*256 + k]*w;
  }
  gxb[(bg*8 + 0)*783 + g] = a0; gxb[(bg*8 + 1)*783 + g] = a1;
  gxb[(bg*8 + 2)*783 + g] = a2; gxb[(bg*8 + 3)*783 + g] = a3;
  gxb[(bg*8 + 4)*783 + g] = a4; gxb[(bg*8 + 5)*783 + g] = a5;
  gxb[(bg*8 + 6)*783 + g] = a6; gxb[(bg*8 + 7)*783 + g] = a7;
}

// ---------------------------------------------------------------------------
// pv_gru_frames: GRU + joint head, 128 WGs x 256 threads, 1 batch/WG.
// Whh bf16 pairs streamed COALESCED from whhPb[kp][row]; gxb/bhh/W1/W2
// staged in LDS (W1 transposed [k][c], W2 transposed stride 12 — both
// conflict-free).  Frames written fp32 to d_out.
// ---------------------------------------------------------------------------
__global__ __launch_bounds__(256) void pv_gru_frames(
    const float* gxb, const unsigned* whhPb, const float* Wih,
    const float* bhh, const float* noise,
    const float* W1, const float* b1, const float* W2, const float* b2,
    float* out)
{
  __shared__ __align__(16) float hs[264];      // h, pads 261..263 = 0
  __shared__ float Dsh[783];
  __shared__ float gxs[783];
  __shared__ float wrt[783*5];                 // Wih[g][256..260]
  __shared__ float bhhn[261];
  __shared__ unsigned short w1t[261*64];       // W1^T [k][c]
  __shared__ float w2t[64*12];                 // W2^T [k][oc], stride 12
  __shared__ float f1p[4*64];                  // layer-1 k-split partials
  const int tid = threadIdx.x;
  const int b = blockIdx.x;

  for (int i = tid; i < 264; i += 256) hs[i] = 0.0f;
  for (int i = tid; i < 783; i += 256) gxs[i] = gxb[b*783 + i];
  for (int i = tid; i < 3915; i += 256) {
    int g = i/5;
    wrt[i] = Wih[g*261 + 256 + (i - g*5)];
  }
  for (int i = tid; i < 261; i += 256) bhhn[i] = bhh[522 + i];
  for (int i = tid; i < 16704; i += 256) {
    int k = i >> 6, c = i & 63;
    w1t[i] = pv_f2b(W1[c*261 + k]);
  }
  for (int i = tid; i < 576; i += 256) {
    int k = i >> 3;  // not used; recompute properly below
  }
  for (int i = tid; i < 576; i += 256) {
    int oc = i % 9;          // i = oc*64 + k ordering of W2
    int k  = (i - oc) / 9;   // careful: W2 is [9][64] row-major: i = oc*64 + k
  }
  // (clean, explicit W2 transpose staging)
  for (int i = tid; i < 576; i += 256) {
    int oc = i >> 6;         // W2 row
    int k  = i & 63;         // W2 col
    w2t[k*12 + oc] = W2[i];
  }
  float hreg0 = 0.0f, hreg1 = 0.0f;
  __syncthreads();

  const int r0 = tid, r1 = tid + 256, r2 = tid + 512;
  const int r3 = 768 + (tid & 15);             // used only when tid < 15

  for (int t = 0; t < 100; ++t) {
    // ---- dot: Dsh[r] = Whh[r] . h  (bf16 weights, coalesced) ----
    {
      float a0=0.f, a1=0.f, a2=0.f, a3=0.f;
      for (int kp = 0; kp < 131; ++kp) {
        const unsigned* wrow = whhPb + kp*784;
        unsigned u0 = wrow[r0];
        unsigned u1 = wrow[r1];
        unsigned u2 = wrow[r2];
        unsigned u3 = wrow[r3];
        float h0 = hs[2*kp], h1 = hs[2*kp + 1];
        a0 += pv_lo(u0)*h0 + pv_hi(u0)*h1;
        a1 += pv_lo(u1)*h0 + pv_hi(u1)*h1;
        a2 += pv_lo(u2)*h0 + pv_hi(u2)*h1;
        a3 += pv_lo(u3)*h0 + pv_hi(u3)*h1;
      }
      Dsh[r0] = a0;
      Dsh[r1] = a1;
      Dsh[r2] = a2;
      if (tid < 15) Dsh[768 + tid] = a3;
    }
    __syncthreads();
    // ---- update: j = tid (0..255) and j = 256+tid for tid<5 ----
    const float tv = (float)t * (1.0f/99.0f);
    const float* nep = noise + (t*128 + b)*4;
    const float n0 = nep[0]*0.1f, n1 = nep[1]*0.1f,
                n2 = nep[2]*0.1f, n3 = nep[3]*0.1f;
    {
      int j = tid;
      const float* wr_ = wrt + j*5;
      const float* wz_ = wrt + (261 + j)*5;
      const float* wn_ = wrt + (522 + j)*5;
      float rterm = n0*wr_[0] + n1*wr_[1] + n2*wr_[2] + n3*wr_[3] + tv*wr_[4];
      float zterm = n0*wz_[0] + n1*wz_[1] + n2*wz_[2] + n3*wz_[3] + tv*wz_[4];
      float nterm = n0*wn_[0] + n1*wn_[1] + n2*wn_[2] + n3*wn_[3] + tv*wn_[4];
      float r_ = pv_sigm(Dsh[j] + gxs[j] + rterm);
      float z_ = pv_sigm(Dsh[261 + j] + gxs[261 + j] + zterm);
      float n_ = pv_tanh(gxs[522 + j] + nterm + r_*(Dsh[522 + j] + bhhn[j]));
      float h = (1.0f - z_)*n_ + z_*hreg0;
      hreg0 = h;
      hs[j] = h;
    }
    if (tid < 5) {
      int j = 256 + tid;
      const float* wr_ = wrt + j*5;
      const float* wz_ = wrt + (261 + j)*5;
      const float* wn_ = wrt + (522 + j)*5;
      float rterm = n0*wr_[0] + n1*wr_[1] + n2*wr_[2] + n3*wr_[3] + tv*wr_[4];
      float zterm = n0*wz_[0] + n1*wz_[1] + n2*wz_[2] + n3*wz_[3] + tv*wz_[4];
      float nterm = n0*wn_[0] + n1*wn_[1] + n2*wn_[2] + n3*wn_[3] + tv*wn_[4];
      float r_ = pv_sigm(Dsh[j] + gxs[j] + rterm);
      float z_ = pv_sigm(Dsh[261 + j] + gxs[261 + j] + zterm);
      float n_ = pv_tanh(gxs[522 + j] + nterm + r_*(Dsh[522 + j] + bhhn[j]));
      float h = (1.0f - z_)*n_ + z_*hreg1;
      hreg1 = h;
      hs[j] = h;
    }
    __syncthreads();
    // ---- joint head layer 1 (k-split 4-way): f1 = leaky(h@W1^T + b1, .2) ----
    {
      const int c = tid & 63;
      const int kseg = tid >> 6;
      const int ks = kseg*66;
      const int ke = (kseg == 3) ? 261 : ks + 66;
      float s = 0.0f;
      for (int k = ks; k < ke; ++k)
        s += pv_b2f(w1t[k*64 + c]) * hs[k];
      f1p[kseg*64 + c] = s;
    }
    __syncthreads();
    if (tid < 64) {
      float s = b1[tid] + f1p[tid] + f1p[64 + tid] + f1p[128 + tid] + f1p[192 + tid];
      f1p[tid] = fmaxf(s, 0.2f*s);
    }
    __syncthreads();
    // ---- joint head layer 2 + sigmoid -> out ----
    if (tid < 9) {
      float s = b2[tid];
      for (int k = 0; k < 64; ++k) s += f1p[k]*w2t[k*12 + tid];
      out[b*900 + t*9 + tid] = pv_sigm(s);
    }
    __syncthreads();
  }
}

// ---------------------------------------------------------------------------
extern "C" __attribute__((visibility("default")))
void kernel_launch(void* const* d_in, const int* in_sizes, int n_in,
                   void* d_out, int out_size, void* d_ws, size_t ws_size,
                   hipStream_t stream)
{
  (void)in_sizes; (void)n_in; (void)out_size; (void)ws_size;
  const float* input_data = (const float*)d_in[0];
  const float* eps        = (const float*)d_in[1];
  const float* noise_eps  = (const float*)d_in[2];
  const float* proj_W     = (const float*)d_in[3];
  const float* proj_b     = (const float*)d_in[4];
  const float* lstm_Wih   = (const float*)d_in[5];
  const float* lstm_Whh   = (const float*)d_in[6];
  const float* lstm_bih   = (const float*)d_in[7];
  const float* lstm_bhh   = (const float*)d_in[8];
  const float* mu_W       = (const float*)d_in[9];
  const float* mu_b       = (const float*)d_in[10];
  const float* lv_W       = (const float*)d_in[11];
  const float* lv_b       = (const float*)d_in[12];
  const float* fcin_W     = (const float*)d_in[13];
  const float* fcin_b     = (const float*)d_in[14];
  const float* gru_Wih    = (const float*)d_in[15];
  const float* gru_Whh    = (const float*)d_in[16];
  const float* gru_bih    = (const float*)d_in[17];
  const float* gru_bhh    = (const float*)d_in[18];
  const float* jf_W1      = (const float*)d_in[19];
  const float* jf_b1      = (const float*)d_in[20];
  const float* jf_W2      = (const float*)d_in[21];
  const float* jf_b2      = (const float*)d_in[22];

  char* w = (char*)d_ws;
  float*    xg    = (float*)(w);                    // 26,214,400 B
  float*    whhT  = (float*)(w + 26214400);         //    262,144 B
  unsigned* whhPb = (unsigned*)(w + 26476544);      //    410,816 B
  float*    hT    = (float*)(w + 26887360);         //     65,536 B
  float*    xvec  = (float*)(w + 26952896);         //    131,072 B
  float*    gxb   = (float*)(w + 27083968);         //    400,896 B (end 27.5 MB)
  float*    outf  = (float*)d_out;

  pv_prep_lstm<<<256, 256, 0, stream>>>(lstm_Whh, whhT);
  pv_prep_gru<<<402, 256, 0, stream>>>(gru_Whh, whhPb);
  pv_gemm<<<dim3(100, 4), 256, 0, stream>>>(input_data, proj_W, proj_b,
                                            lstm_Wih, lstm_bih, lstm_bhh, xg);
  pv_lstm<<<64, 256, 0, stream>>>(xg, whhT, hT);
  pv_head<<<128, 64, 0, stream>>>(hT, eps, mu_W, mu_b, lv_W, lv_b,
                                  fcin_W, fcin_b, xvec, outf);
  pv_gxbase<<<dim3(16, 4), 256, 0, stream>>>(xvec, gru_Wih, gru_bih, gru_bhh, gxb);
  pv_gru_frames<<<128, 256, 0, stream>>>(gxb, whhPb, gru_Wih, gru_bhh, noise_eps,
                                         jf_W1, jf_b1, jf_W2, jf_b2, outf);
}

// Round 10
// 1494.496 us; speedup vs baseline: 4.6252x; 1.7437x over previous
//
#include <hip/hip_runtime.h>
#include <hip/hip_bf16.h>

typedef float f32x4 __attribute__((ext_vector_type(4)));
typedef short s16x8 __attribute__((ext_vector_type(8)));

__device__ __forceinline__ float pv_sigm(float x){ return 1.0f/(1.0f + __expf(-x)); }
__device__ __forceinline__ float pv_tanh(float x){ float e = __expf(2.0f*x); return 1.0f - 2.0f/(e + 1.0f); }

__device__ __forceinline__ unsigned short pv_f2b(float x){
  union { float f; unsigned u; } c; c.f = x;
  unsigned r = (c.u + 0x7fffu + ((c.u >> 16) & 1u)) >> 16;
  return (unsigned short)r;
}
__device__ __forceinline__ unsigned pv_pack2(float a, float b){
  return ((unsigned)pv_f2b(b) << 16) | (unsigned)pv_f2b(a);
}
__device__ __forceinline__ float pv_lo(unsigned u){
  union { unsigned u; float f; } c; c.u = u << 16; return c.f;
}
__device__ __forceinline__ float pv_hi(unsigned u){
  union { unsigned u; float f; } c; c.u = u & 0xffff0000u; return c.f;
}

// manual OCP e4m3fn encode (RNE); valid for |x| < 448
__device__ __forceinline__ unsigned char pv_fp8(float x){
  union { float f; unsigned u; } c; c.f = x;
  unsigned s = (c.u >> 24) & 0x80u;
  unsigned au = c.u & 0x7fffffffu;
  if (au == 0u) return (unsigned char)s;
  int ex = (int)(au >> 23) - 127;
  if (ex < -6) ex = -6;
  union { unsigned u; float f; } iv; iv.u = (unsigned)(3 - ex + 127) << 23;
  union { unsigned u; float f; } a;  a.u = au;
  int q = (int)rintf(a.f * iv.f);
  if (q >= 16) { q >>= 1; ex += 1; }
  unsigned bits;
  if (ex == -6 && q < 8) bits = (unsigned)q;
  else bits = (unsigned)(((ex + 7) << 3) | (q - 8));
  return (unsigned char)(s | bits);
}

// ---------------------------------------------------------------------------
// pv_prep_lstm: transpose lstm_Whh (512x128) -> whhT[k][g] (128x512)
// ---------------------------------------------------------------------------
__global__ void pv_prep_lstm(const float* Whh, float* whhT){
  int idx = blockIdx.x*256 + threadIdx.x;
  if (idx < 65536) {
    int k = idx >> 9;
    int g = idx & 511;
    whhT[idx] = Whh[g*128 + k];
  }
}

// ---------------------------------------------------------------------------
// pv_prep_gru8: pack gru weights into fp8 MFMA B-fragment order.
// 49 gate-tiles of 16 x 9 K-chunks of 32 x 64 lanes; each entry = 8 fp8.
// Fragment value for (tile T, chunk c, lane l, byte e):
//   n = T*16 + (l&15), k = c*32 + (l>>4)*8 + e
//   k<261        -> 8*Whh[n][k]
//   261<=k<266   -> (n<522) ? 8*Wih[n][256+k-261] : 0   (noise/time for r,z)
//   else 0
// ---------------------------------------------------------------------------
__global__ void pv_prep_gru8(const float* Whh, const float* Wih,
                             unsigned long long* wfp8){
  int idx = blockIdx.x*256 + threadIdx.x;   // < 49*9*64 = 28224
  if (idx >= 28224) return;
  int T = idx / 576;
  int rem = idx - T*576;
  int c = rem >> 6;
  int l = rem & 63;
  int n = T*16 + (l & 15);
  int quad = l >> 4;
  unsigned long long v = 0ull;
  #pragma unroll
  for (int e = 0; e < 8; ++e) {
    int k = c*32 + quad*8 + e;
    float w = 0.0f;
    if (n < 783) {
      if (k < 261) w = Whh[n*261 + k];
      else if (k < 266 && n < 522) w = Wih[n*261 + 256 + (k - 261)];
    }
    v |= (unsigned long long)pv_fp8(8.0f*w) << (8*e);
  }
  wfp8[idx] = v;
}

// ---------------------------------------------------------------------------
// pv_gemm: xg = leaky(pose @ projW^T + projb, 0.1) @ lstm_Wih^T + bih + bhh
// bf16 MFMA 16x16x32, 128x128 tile, BK=32. (unchanged from round 9)
// ---------------------------------------------------------------------------
__global__ __launch_bounds__(256) void pv_gemm(
    const float* pose, const float* projW, const float* projb,
    const float* Wih, const float* bih, const float* bhh,
    float* xg)
{
  __shared__ __align__(16) unsigned As[128*24];
  __shared__ __align__(16) unsigned Bs[128*24];
  __shared__ float Ws[320];

  const int tid = threadIdx.x;
  const int m0 = blockIdx.x * 128;
  const int n0 = blockIdx.y * 128;

  const int rl = tid >> 1;
  const int kh = tid & 1;
  float p0,p1,p2,p3,p4,p5,p6,p7,p8;
  {
    const float* pr = pose + (m0 + rl) * 9;
    p0=pr[0]; p1=pr[1]; p2=pr[2]; p3=pr[3]; p4=pr[4];
    p5=pr[5]; p6=pr[6]; p7=pr[7]; p8=pr[8];
  }

  const int wave = tid >> 6;
  const int lane = tid & 63;
  const int wm = wave >> 1, wn = wave & 1;
  const int l16 = lane & 15, quad = lane >> 4;

  f32x4 acc[4][4];
  #pragma unroll
  for (int i = 0; i < 4; ++i)
    #pragma unroll
    for (int j = 0; j < 4; ++j) acc[i][j] = (f32x4){0.f,0.f,0.f,0.f};

  for (int kk = 0; kk < 128; ++kk) {
    __syncthreads();
    for (int idx = tid; idx < 320; idx += 256)
      Ws[idx] = (idx < 288) ? projW[kk*288 + idx] : projb[kk*32 + (idx - 288)];
    #pragma unroll
    for (int i = 0; i < 8; ++i) {
      int q = tid + i*256;
      int nl = q >> 4;
      int kp = q & 15;
      const float* src = Wih + (n0 + nl)*4096 + kk*32 + kp*2;
      Bs[nl*24 + kp] = pv_pack2(src[0], src[1]);
    }
    __syncthreads();
    {
      const int kbase = kh*16;
      const float* wbase = Ws + kbase*9;
      float av[16];
      #pragma unroll
      for (int u = 0; u < 16; ++u) {
        const float* wr = wbase + u*9;
        float s = Ws[288 + kbase + u]
                + p0*wr[0] + p1*wr[1] + p2*wr[2] + p3*wr[3] + p4*wr[4]
                + p5*wr[5] + p6*wr[6] + p7*wr[7] + p8*wr[8];
        av[u] = fmaxf(s, 0.1f*s);
      }
      #pragma unroll
      for (int q = 0; q < 8; ++q)
        As[rl*24 + kh*8 + q] = pv_pack2(av[2*q], av[2*q+1]);
    }
    __syncthreads();
    const unsigned short* As16 = (const unsigned short*)As;
    const unsigned short* Bs16 = (const unsigned short*)Bs;
    s16x8 af[4], bfv[4];
    #pragma unroll
    for (int i = 0; i < 4; ++i)
      af[i] = *(const s16x8*)(As16 + (wm*64 + i*16 + l16)*48 + quad*8);
    #pragma unroll
    for (int j = 0; j < 4; ++j)
      bfv[j] = *(const s16x8*)(Bs16 + (wn*64 + j*16 + l16)*48 + quad*8);
    #pragma unroll
    for (int i = 0; i < 4; ++i)
      #pragma unroll
      for (int j = 0; j < 4; ++j)
        acc[i][j] = __builtin_amdgcn_mfma_f32_16x16x32_bf16(af[i], bfv[j], acc[i][j], 0, 0, 0);
  }
  #pragma unroll
  for (int j = 0; j < 4; ++j) {
    int col = n0 + wn*64 + j*16 + l16;
    float bsum = bih[col] + bhh[col];
    #pragma unroll
    for (int i = 0; i < 4; ++i) {
      #pragma unroll
      for (int r = 0; r < 4; ++r) {
        int row = m0 + wm*64 + i*16 + quad*4 + r;
        int bb = row / 100;
        int tt = row - bb*100;
        xg[(tt*128 + bb)*512 + col] = acc[i][j][r] + bsum;
      }
    }
  }
}

// ---------------------------------------------------------------------------
// pv_lstm: unchanged from round 9 (Whh fp32 in VGPRs).
// ---------------------------------------------------------------------------
__global__ __launch_bounds__(256, 1) void pv_lstm(
    const float* xg, const float* whhT, float* hT)
{
  __shared__ __align__(16) float hs[2*128];
  __shared__ float Ds[2*512];
  const int tid = threadIdx.x;
  const int m0 = blockIdx.x * 2;
  const int g0 = tid, g1 = tid + 256;
  const int um = tid >> 7, uj = tid & 127;

  float wv0[128], wv1[128];
  #pragma unroll
  for (int k = 0; k < 128; ++k) wv0[k] = whhT[k*512 + g0];
  #pragma unroll
  for (int k = 0; k < 128; ++k) wv1[k] = whhT[k*512 + g1];

  hs[tid] = 0.0f;
  float creg = 0.0f;
  __syncthreads();

  const f32x4* h40 = (const f32x4*)hs;
  const f32x4* h41 = (const f32x4*)(hs + 128);

  for (int t = 0; t < 100; ++t) {
    float d00=0.f, d01=0.f, d10=0.f, d11=0.f;
    #pragma unroll
    for (int k4 = 0; k4 < 32; ++k4) {
      f32x4 ha = h40[k4];
      f32x4 hb = h41[k4];
      #pragma unroll
      for (int e = 0; e < 4; ++e) {
        float w0 = wv0[k4*4 + e], w1 = wv1[k4*4 + e];
        d00 += w0*ha[e]; d01 += w0*hb[e];
        d10 += w1*ha[e]; d11 += w1*hb[e];
      }
    }
    const float* xb = xg + (t*128 + m0)*512;
    d00 += xb[g0];
    d10 += xb[g1];
    d01 += xb[512 + g0];
    d11 += xb[512 + g1];
    Ds[g0] = d00; Ds[g1] = d10; Ds[512 + g0] = d01; Ds[512 + g1] = d11;
    __syncthreads();
    {
      float gi = Ds[um*512 + uj];
      float gf = Ds[um*512 + 128 + uj];
      float gg = Ds[um*512 + 256 + uj];
      float go = Ds[um*512 + 384 + uj];
      float c = pv_sigm(gf)*creg + pv_sigm(gi)*pv_tanh(gg);
      creg = c;
      float h = pv_sigm(go)*pv_tanh(c);
      hs[um*128 + uj] = h;
      if (t == 99) hT[(m0 + um)*128 + uj] = h;
    }
    __syncthreads();
  }
}

// ---------------------------------------------------------------------------
// pv_head: unchanged.
// ---------------------------------------------------------------------------
__global__ __launch_bounds__(64) void pv_head(
    const float* hT, const float* eps,
    const float* muW, const float* mub,
    const float* lvW, const float* lvb,
    const float* fcW, const float* fcb,
    float* xvec, float* out)
{
  __shared__ float hrow[128];
  __shared__ float emb[64];
  const int b = blockIdx.x, j = threadIdx.x;
  hrow[j] = hT[b*128 + j];
  hrow[j + 64] = hT[b*128 + 64 + j];
  __syncthreads();
  float sm = mub[j], sl = lvb[j];
  for (int k = 0; k < 128; ++k) {
    sm += hrow[k]*muW[j*128 + k];
    sl += hrow[k]*lvW[j*128 + k];
  }
  float mu = fmaxf(sm, 0.1f*sm);
  float lv = fmaxf(sl, 0.1f*sl);
  lv = fminf(fmaxf(lv, -10.0f), 10.0f);
  float em = mu + eps[b*64 + j]*__expf(0.5f*lv);
  emb[j] = em;
  out[115200 + b*64 + j] = mu;
  out[123392 + b*64 + j] = lv;
  __syncthreads();
  for (int c4 = 0; c4 < 4; ++c4) {
    int c = c4*64 + j;
    float s = fcb[c];
    for (int k = 0; k < 64; ++k) s += emb[k]*fcW[c*64 + k];
    xvec[b*256 + c] = s;
  }
}

// ---------------------------------------------------------------------------
// pv_gxbase: unchanged.
// ---------------------------------------------------------------------------
__global__ __launch_bounds__(256) void pv_gxbase(
    const float* xvec, const float* Wih,
    const float* bih, const float* bhh, float* gxb)
{
  __shared__ float xs[8*256];
  const int tid = threadIdx.x;
  const int bg = blockIdx.x;
  const int gg = blockIdx.y;
  for (int i = tid; i < 2048; i += 256) xs[i] = xvec[bg*2048 + i];
  __syncthreads();
  const int g = gg*256 + tid;
  if (g >= 783) return;
  float bias = bih[g] + ((g < 522) ? bhh[g] : 0.0f);
  float a0=bias,a1=bias,a2=bias,a3=bias,a4=bias,a5=bias,a6=bias,a7=bias;
  const float* wr = Wih + g*261;
  for (int k = 0; k < 256; ++k) {
    float w = wr[k];
    a0 += xs[0*256 + k]*w; a1 += xs[1*256 + k]*w;
    a2 += xs[2*256 + k]*w; a3 += xs[3*256 + k]*w;
    a4 += xs[4*256 + k]*w; a5 += xs[5*256 + k]*w;
    a6 += xs[6*256 + k]*w; a7 += xs[7*256 + k]*w;
  }
  gxb[(bg*8 + 0)*783 + g] = a0; gxb[(bg*8 + 1)*783 + g] = a1;
  gxb[(bg*8 + 2)*783 + g] = a2; gxb[(bg*8 + 3)*783 + g] = a3;
  gxb[(bg*8 + 4)*783 + g] = a4; gxb[(bg*8 + 5)*783 + g] = a5;
  gxb[(bg*8 + 6)*783 + g] = a6; gxb[(bg*8 + 7)*783 + g] = a7;
}

// ---------------------------------------------------------------------------
// pv_gru: 8 WGs x 1024 threads, 16 batches/WG.  Whh as fp8 e4m3 MFMA
// B-fragments RESIDENT IN VGPRS (x8 scale); h/noise/time in A (x4 scale,
// K=261+5 -> 288); D /= 32.  noise/time for r,z ride the MFMA; n-gate
// noise/time + bhh_n handled in the update (r*(gh_n) separation).
// Writes hseq fp32 [t][b][261].
// ---------------------------------------------------------------------------
__global__ __launch_bounds__(1024) void pv_gru(
    const float* gxb, const unsigned long long* wfp8, const float* Wih,
    const float* bhh, const float* noise, float* hseq)
{
  __shared__ __align__(16) unsigned char Afp8[16*296];  // A fp8, row stride 296
  __shared__ float Ds[16*788];                          // D, row stride 788
  __shared__ float WihN[261*5];                         // n-gate noise/time weights
  __shared__ float bhhN[261];

  const int tid = threadIdx.x;
  const int wv = tid >> 6;
  const int lane = tid & 63;
  const int l16 = lane & 15, quad = lane >> 4;
  const int m0 = blockIdx.x * 16;
  const int tbase = (wv < 15) ? wv*3 : 45;
  const int ntiles = (wv < 15) ? 3 : 4;     // 49 tiles of 16 over 784 gates

  long bfr[4][9];
  #pragma unroll
  for (int tt = 0; tt < 4; ++tt) {
    if (tt < ntiles) {
      #pragma unroll
      for (int c = 0; c < 9; ++c)
        bfr[tt][c] = (long)wfp8[((tbase + tt)*9 + c)*64 + lane];
    } else {
      #pragma unroll
      for (int c = 0; c < 9; ++c) bfr[tt][c] = 0;
    }
  }
  for (int i = tid; i < 261*5; i += 1024) WihN[i] = Wih[(522 + i/5)*261 + 256 + (i % 5)];
  for (int i = tid; i < 261; i += 1024) bhhN[i] = bhh[522 + i];
  for (int i = tid; i < 16*296; i += 1024) Afp8[i] = 0;
  __syncthreads();
  if (tid < 80) {   // A noise/time columns for t=0 (time_0 = 0)
    const int m = tid/5, i = tid - (tid/5)*5;
    float v = (i < 4) ? noise[(m0 + m)*4 + i]*0.1f : 0.0f;
    Afp8[m*296 + 261 + i] = pv_fp8(4.0f*v);
  }
  float hreg[5] = {0,0,0,0,0};
  __syncthreads();

  for (int t = 0; t < 100; ++t) {
    f32x4 acc[4];
    #pragma unroll
    for (int tt = 0; tt < 4; ++tt) acc[tt] = (f32x4){0,0,0,0};
    #pragma unroll
    for (int c = 0; c < 9; ++c) {
      const long a = *(const long*)(Afp8 + l16*296 + c*32 + quad*8);
      #pragma unroll
      for (int tt = 0; tt < 4; ++tt)
        if (tt < ntiles)
          acc[tt] = __builtin_amdgcn_mfma_f32_16x16x32_fp8_fp8(a, bfr[tt][c], acc[tt], 0, 0, 0);
    }
    #pragma unroll
    for (int tt = 0; tt < 4; ++tt)
      if (tt < ntiles) {
        const int n = (tbase + tt)*16 + l16;
        #pragma unroll
        for (int r = 0; r < 4; ++r)
          Ds[(quad*4 + r)*788 + n] = acc[tt][r];
      }
    __syncthreads();
    const float inv32 = 1.0f/32.0f;
    const float tv = (float)t * (1.0f/99.0f);
    #pragma unroll
    for (int e = 0; e < 5; ++e) {
      const int el = tid + e*1024;
      if (el < 4176) {
        const int m = el/261, j = el - (el/261)*261;
        const float* dr = Ds + m*788;
        float Dr = dr[j]*inv32, Dz = dr[261 + j]*inv32, Dn = dr[522 + j]*inv32;
        const float* gb = gxb + (m0 + m)*783;
        const float* wn = WihN + j*5;
        const float* ne = noise + (t*128 + m0 + m)*4;
        float gn = gb[522 + j]
                 + 0.1f*(ne[0]*wn[0] + ne[1]*wn[1] + ne[2]*wn[2] + ne[3]*wn[3])
                 + tv*wn[4];
        float r_ = pv_sigm(Dr + gb[j]);
        float z_ = pv_sigm(Dz + gb[261 + j]);
        float n_ = pv_tanh(gn + r_*(Dn + bhhN[j]));
        float h = (1.0f - z_)*n_ + z_*hreg[e];
        hreg[e] = h;
        hseq[(t*128 + m0 + m)*261 + j] = h;
        Afp8[m*296 + j] = pv_fp8(4.0f*h);
      }
    }
    if (tid < 80 && t < 99) {   // A noise/time for t+1
      const int m = tid/5, i = tid - (tid/5)*5;
      float v = (i < 4) ? noise[((t+1)*128 + m0 + m)*4 + i]*0.1f
                        : (t+1)*(1.0f/99.0f);
      Afp8[m*296 + 261 + i] = pv_fp8(4.0f*v);
    }
    __syncthreads();
  }
}

// ---------------------------------------------------------------------------
// pv_frames: frames = sigmoid(leaky(h@W1^T + b1, 0.2)@W2^T + b2)
// from hseq fp32 (T,B,261); 800 WGs x 256 thr, 16 rows each.
// W1 staged bf16-paired [c][kp] stride 133 (conflict-free).
// ---------------------------------------------------------------------------
__global__ __launch_bounds__(256) void pv_frames(
    const float* hseq, const float* W1, const float* b1,
    const float* W2, const float* b2, float* out)
{
  __shared__ __align__(16) float h16[16*264];
  __shared__ unsigned w1p[64*133];
  __shared__ float f1s[16*66];
  __shared__ float w2s[576];
  const int tid = threadIdx.x;
  const int r0 = blockIdx.x * 16;    // rows rt = t*128 + b
  for (int i = tid; i < 16*264; i += 256) {
    int r = i / 264, k = i - r*264;
    h16[i] = (k < 261) ? hseq[(r0 + r)*261 + k] : 0.0f;
  }
  for (int i = tid; i < 64*131; i += 256) {
    int c = i/131, kp = i - (i/131)*131;
    int k = kp*2;
    float a0 = W1[c*261 + k];
    float a1 = (k + 1 < 261) ? W1[c*261 + k + 1] : 0.0f;
    w1p[c*133 + kp] = pv_pack2(a0, a1);
  }
  for (int i = tid; i < 576; i += 256) w2s[i] = W2[i];
  __syncthreads();
  #pragma unroll
  for (int e = 0; e < 4; ++e) {
    const int el = tid + e*256;
    const int r = el >> 6, c = el & 63;
    float s = b1[c];
    const unsigned* wp = w1p + c*133;
    const float* hr = h16 + r*264;
    for (int kp = 0; kp < 131; ++kp) {
      unsigned w = wp[kp];
      s += pv_lo(w)*hr[2*kp] + pv_hi(w)*hr[2*kp + 1];
    }
    f1s[r*66 + c] = fmaxf(s, 0.2f*s);
  }
  __syncthreads();
  if (tid < 144) {
    const int r = tid/9, oc = tid - (tid/9)*9;
    float s = b2[oc];
    const float* fr = f1s + r*66;
    const float* w = w2s + oc*64;
    #pragma unroll 8
    for (int k = 0; k < 64; ++k) s += fr[k]*w[k];
    const int rt = r0 + r;
    const int tt = rt >> 7, bb = rt & 127;
    out[bb*900 + tt*9 + oc] = pv_sigm(s);
  }
}

// ---------------------------------------------------------------------------
extern "C" __attribute__((visibility("default")))
void kernel_launch(void* const* d_in, const int* in_sizes, int n_in,
                   void* d_out, int out_size, void* d_ws, size_t ws_size,
                   hipStream_t stream)
{
  (void)in_sizes; (void)n_in; (void)out_size; (void)ws_size;
  const float* input_data = (const float*)d_in[0];
  const float* eps        = (const float*)d_in[1];
  const float* noise_eps  = (const float*)d_in[2];
  const float* proj_W     = (const float*)d_in[3];
  const float* proj_b     = (const float*)d_in[4];
  const float* lstm_Wih   = (const float*)d_in[5];
  const float* lstm_Whh   = (const float*)d_in[6];
  const float* lstm_bih   = (const float*)d_in[7];
  const float* lstm_bhh   = (const float*)d_in[8];
  const float* mu_W       = (const float*)d_in[9];
  const float* mu_b       = (const float*)d_in[10];
  const float* lv_W       = (const float*)d_in[11];
  const float* lv_b       = (const float*)d_in[12];
  const float* fcin_W     = (const float*)d_in[13];
  const float* fcin_b     = (const float*)d_in[14];
  const float* gru_Wih    = (const float*)d_in[15];
  const float* gru_Whh    = (const float*)d_in[16];
  const float* gru_bih    = (const float*)d_in[17];
  const float* gru_bhh    = (const float*)d_in[18];
  const float* jf_W1      = (const float*)d_in[19];
  const float* jf_b1      = (const float*)d_in[20];
  const float* jf_W2      = (const float*)d_in[21];
  const float* jf_b2      = (const float*)d_in[22];

  char* w = (char*)d_ws;
  float*              xg   = (float*)(w);                 // 26,214,400 B
  float*              whhT = (float*)(w + 26214400);      //    262,144 B
  unsigned long long* wfp8 = (unsigned long long*)(w + 26476544);  // 225,792 B
  float*              hT   = (float*)(w + 26702336);      //     65,536 B
  float*              xvec = (float*)(w + 26767872);      //    131,072 B
  float*              gxb  = (float*)(w + 26898944);      //    400,896 B
  float*              hseq = (float*)(w + 27299840);      // 13,363,200 B (end 40.7 MB)
  float*              outf = (float*)d_out;

  pv_prep_lstm<<<256, 256, 0, stream>>>(lstm_Whh, whhT);
  pv_prep_gru8<<<111, 256, 0, stream>>>(gru_Whh, gru_Wih, wfp8);
  pv_gemm<<<dim3(100, 4), 256, 0, stream>>>(input_data, proj_W, proj_b,
                                            lstm_Wih, lstm_bih, lstm_bhh, xg);
  pv_lstm<<<64, 256, 0, stream>>>(xg, whhT, hT);
  pv_head<<<128, 64, 0, stream>>>(hT, eps, mu_W, mu_b, lv_W, lv_b,
                                  fcin_W, fcin_b, xvec, outf);
  pv_gxbase<<<dim3(16, 4), 256, 0, stream>>>(xvec, gru_Wih, gru_bih, gru_bhh, gxb);
  pv_gru<<<8, 1024, 0, stream>>>(gxb, wfp8, gru_Wih, gru_bhh, noise_eps, hseq);
  pv_frames<<<800, 256, 0, stream>>>(hseq, jf_W1, jf_b1, jf_W2, jf_b2, outf);
}

// Round 11
// 1322.757 us; speedup vs baseline: 5.2257x; 1.1298x over previous
//
#include <hip/hip_runtime.h>
#include <hip/hip_bf16.h>

typedef float f32x4 __attribute__((ext_vector_type(4)));
typedef short s16x8 __attribute__((ext_vector_type(8)));

__device__ __forceinline__ float pv_sigm(float x){ return 1.0f/(1.0f + __expf(-x)); }
__device__ __forceinline__ float pv_tanh(float x){ float e = __expf(2.0f*x); return 1.0f - 2.0f/(e + 1.0f); }

__device__ __forceinline__ unsigned short pv_f2b(float x){
  union { float f; unsigned u; } c; c.f = x;
  unsigned r = (c.u + 0x7fffu + ((c.u >> 16) & 1u)) >> 16;
  return (unsigned short)r;
}
__device__ __forceinline__ unsigned pv_pack2(float a, float b){
  return ((unsigned)pv_f2b(b) << 16) | (unsigned)pv_f2b(a);
}
__device__ __forceinline__ float pv_lo(unsigned u){
  union { unsigned u; float f; } c; c.u = u << 16; return c.f;
}
__device__ __forceinline__ float pv_hi(unsigned u){
  union { unsigned u; float f; } c; c.u = u & 0xffff0000u; return c.f;
}

// manual OCP e4m3fn encode (RNE); valid for |x| < 448
__device__ __forceinline__ unsigned char pv_fp8(float x){
  union { float f; unsigned u; } c; c.f = x;
  unsigned s = (c.u >> 24) & 0x80u;
  unsigned au = c.u & 0x7fffffffu;
  if (au == 0u) return (unsigned char)s;
  int ex = (int)(au >> 23) - 127;
  if (ex < -6) ex = -6;
  union { unsigned u; float f; } iv; iv.u = (unsigned)(3 - ex + 127) << 23;
  union { unsigned u; float f; } a;  a.u = au;
  int q = (int)rintf(a.f * iv.f);
  if (q >= 16) { q >>= 1; ex += 1; }
  unsigned bits;
  if (ex == -6 && q < 8) bits = (unsigned)q;
  else bits = (unsigned)(((ex + 7) << 3) | (q - 8));
  return (unsigned char)(s | bits);
}

// ---------------------------------------------------------------------------
// pv_prep_gru8: pack gru weights into fp8 MFMA B-fragment order.
// 49 gate-tiles of 16 x 9 K-chunks of 32 x 64 lanes; each entry = 8 fp8.
//   n = T*16 + (l&15), k = c*32 + (l>>4)*8 + e
//   k<261        -> 8*Whh[n][k]
//   261<=k<266   -> (n<522) ? 8*Wih[n][256+k-261] : 0   (noise/time for r,z)
// ---------------------------------------------------------------------------
__global__ void pv_prep_gru8(const float* Whh, const float* Wih,
                             unsigned long long* wfp8){
  int idx = blockIdx.x*256 + threadIdx.x;   // < 49*9*64 = 28224
  if (idx >= 28224) return;
  int T = idx / 576;
  int rem = idx - T*576;
  int c = rem >> 6;
  int l = rem & 63;
  int n = T*16 + (l & 15);
  int quad = l >> 4;
  unsigned long long v = 0ull;
  #pragma unroll
  for (int e = 0; e < 8; ++e) {
    int k = c*32 + quad*8 + e;
    float w = 0.0f;
    if (n < 783) {
      if (k < 261) w = Whh[n*261 + k];
      else if (k < 266 && n < 522) w = Wih[n*261 + 256 + (k - 261)];
    }
    v |= (unsigned long long)pv_fp8(8.0f*w) << (8*e);
  }
  wfp8[idx] = v;
}

// ---------------------------------------------------------------------------
// pv_gemm: xg = leaky(pose @ projW^T + projb, 0.1) @ lstm_Wih^T + bih + bhh
// bf16 MFMA 16x16x32, 128x128 tile, BK=32. (unchanged)
// ---------------------------------------------------------------------------
__global__ __launch_bounds__(256) void pv_gemm(
    const float* pose, const float* projW, const float* projb,
    const float* Wih, const float* bih, const float* bhh,
    float* xg)
{
  __shared__ __align__(16) unsigned As[128*24];
  __shared__ __align__(16) unsigned Bs[128*24];
  __shared__ float Ws[320];

  const int tid = threadIdx.x;
  const int m0 = blockIdx.x * 128;
  const int n0 = blockIdx.y * 128;

  const int rl = tid >> 1;
  const int kh = tid & 1;
  float p0,p1,p2,p3,p4,p5,p6,p7,p8;
  {
    const float* pr = pose + (m0 + rl) * 9;
    p0=pr[0]; p1=pr[1]; p2=pr[2]; p3=pr[3]; p4=pr[4];
    p5=pr[5]; p6=pr[6]; p7=pr[7]; p8=pr[8];
  }

  const int wave = tid >> 6;
  const int lane = tid & 63;
  const int wm = wave >> 1, wn = wave & 1;
  const int l16 = lane & 15, quad = lane >> 4;

  f32x4 acc[4][4];
  #pragma unroll
  for (int i = 0; i < 4; ++i)
    #pragma unroll
    for (int j = 0; j < 4; ++j) acc[i][j] = (f32x4){0.f,0.f,0.f,0.f};

  for (int kk = 0; kk < 128; ++kk) {
    __syncthreads();
    for (int idx = tid; idx < 320; idx += 256)
      Ws[idx] = (idx < 288) ? projW[kk*288 + idx] : projb[kk*32 + (idx - 288)];
    #pragma unroll
    for (int i = 0; i < 8; ++i) {
      int q = tid + i*256;
      int nl = q >> 4;
      int kp = q & 15;
      const float* src = Wih + (n0 + nl)*4096 + kk*32 + kp*2;
      Bs[nl*24 + kp] = pv_pack2(src[0], src[1]);
    }
    __syncthreads();
    {
      const int kbase = kh*16;
      const float* wbase = Ws + kbase*9;
      float av[16];
      #pragma unroll
      for (int u = 0; u < 16; ++u) {
        const float* wr = wbase + u*9;
        float s = Ws[288 + kbase + u]
                + p0*wr[0] + p1*wr[1] + p2*wr[2] + p3*wr[3] + p4*wr[4]
                + p5*wr[5] + p6*wr[6] + p7*wr[7] + p8*wr[8];
        av[u] = fmaxf(s, 0.1f*s);
      }
      #pragma unroll
      for (int q = 0; q < 8; ++q)
        As[rl*24 + kh*8 + q] = pv_pack2(av[2*q], av[2*q+1]);
    }
    __syncthreads();
    const unsigned short* As16 = (const unsigned short*)As;
    const unsigned short* Bs16 = (const unsigned short*)Bs;
    s16x8 af[4], bfv[4];
    #pragma unroll
    for (int i = 0; i < 4; ++i)
      af[i] = *(const s16x8*)(As16 + (wm*64 + i*16 + l16)*48 + quad*8);
    #pragma unroll
    for (int j = 0; j < 4; ++j)
      bfv[j] = *(const s16x8*)(Bs16 + (wn*64 + j*16 + l16)*48 + quad*8);
    #pragma unroll
    for (int i = 0; i < 4; ++i)
      #pragma unroll
      for (int j = 0; j < 4; ++j)
        acc[i][j] = __builtin_amdgcn_mfma_f32_16x16x32_bf16(af[i], bfv[j], acc[i][j], 0, 0, 0);
  }
  #pragma unroll
  for (int j = 0; j < 4; ++j) {
    int col = n0 + wn*64 + j*16 + l16;
    float bsum = bih[col] + bhh[col];
    #pragma unroll
    for (int i = 0; i < 4; ++i) {
      #pragma unroll
      for (int r = 0; r < 4; ++r) {
        int row = m0 + wm*64 + i*16 + quad*4 + r;
        int bb = row / 100;
        int tt = row - bb*100;
        xg[(tt*128 + bb)*512 + col] = acc[i][j][r] + bsum;
      }
    }
  }
}

// ---------------------------------------------------------------------------
// pv_lstm (MFMA): 8 WGs x 1024 threads, 16 batches/WG.  Whh (512x128) bf16
// B-fragments RESIDENT IN VGPRS (wave wv owns gate-tiles {2wv, 2wv+1};
// bfr = 32 VGPRs).  h bf16 in LDS; 16x16x32 bf16 MFMA.
// launch_bounds(1024,4) -> 128-VGPR cap, no spill.
// ---------------------------------------------------------------------------
__global__ __launch_bounds__(1024, 4) void pv_lstm(
    const float* xg, const float* Whh, float* hT)
{
  __shared__ __align__(16) unsigned short Hs[16*136];  // h bf16, row stride 136
  __shared__ float Ds[16*544];                         // gates (D + xg)
  const int tid = threadIdx.x;
  const int wv = tid >> 6;
  const int lane = tid & 63;
  const int l16 = lane & 15, quad = lane >> 4;
  const int m0 = blockIdx.x * 16;

  s16x8 bfr[2][4];
  #pragma unroll
  for (int tt = 0; tt < 2; ++tt) {
    const int g = (wv*2 + tt)*16 + l16;
    #pragma unroll
    for (int c = 0; c < 4; ++c) {
      s16x8 v;
      #pragma unroll
      for (int e = 0; e < 8; ++e)
        v[e] = (short)pv_f2b(Whh[g*128 + c*32 + quad*8 + e]);
      bfr[tt][c] = v;
    }
  }
  for (int i = tid; i < 16*136; i += 1024) Hs[i] = 0;
  float cst[2] = {0.0f, 0.0f};
  __syncthreads();

  for (int t = 0; t < 100; ++t) {
    // prefetch xg[t] (hidden behind MFMA phase)
    float xv[2][4];
    #pragma unroll
    for (int tt = 0; tt < 2; ++tt) {
      const int g = (wv*2 + tt)*16 + l16;
      #pragma unroll
      for (int r = 0; r < 4; ++r)
        xv[tt][r] = xg[(t*128 + m0 + quad*4 + r)*512 + g];
    }
    f32x4 acc0 = {0,0,0,0}, acc1 = {0,0,0,0};
    #pragma unroll
    for (int c = 0; c < 4; ++c) {
      s16x8 a = *(const s16x8*)(Hs + l16*136 + c*32 + quad*8);
      acc0 = __builtin_amdgcn_mfma_f32_16x16x32_bf16(a, bfr[0][c], acc0, 0, 0, 0);
      acc1 = __builtin_amdgcn_mfma_f32_16x16x32_bf16(a, bfr[1][c], acc1, 0, 0, 0);
    }
    #pragma unroll
    for (int r = 0; r < 4; ++r) {
      Ds[(quad*4 + r)*544 + (wv*2 + 0)*16 + l16] = acc0[r] + xv[0][r];
      Ds[(quad*4 + r)*544 + (wv*2 + 1)*16 + l16] = acc1[r] + xv[1][r];
    }
    __syncthreads();
    // gate update: 2048 elements (16 batches x 128 hidden)
    #pragma unroll
    for (int e = 0; e < 2; ++e) {
      const int el = tid + e*1024;
      const int m = el >> 7, j = el & 127;
      float gi = Ds[m*544 + j];
      float gf = Ds[m*544 + 128 + j];
      float gg = Ds[m*544 + 256 + j];
      float go = Ds[m*544 + 384 + j];
      float c = pv_sigm(gf)*cst[e] + pv_sigm(gi)*pv_tanh(gg);
      cst[e] = c;
      float h = pv_sigm(go)*pv_tanh(c);
      Hs[m*136 + j] = pv_f2b(h);
      if (t == 99) hT[(m0 + m)*128 + j] = h;
    }
    __syncthreads();
  }
}

// ---------------------------------------------------------------------------
// pv_head: unchanged.
// ---------------------------------------------------------------------------
__global__ __launch_bounds__(64) void pv_head(
    const float* hT, const float* eps,
    const float* muW, const float* mub,
    const float* lvW, const float* lvb,
    const float* fcW, const float* fcb,
    float* xvec, float* out)
{
  __shared__ float hrow[128];
  __shared__ float emb[64];
  const int b = blockIdx.x, j = threadIdx.x;
  hrow[j] = hT[b*128 + j];
  hrow[j + 64] = hT[b*128 + 64 + j];
  __syncthreads();
  float sm = mub[j], sl = lvb[j];
  for (int k = 0; k < 128; ++k) {
    sm += hrow[k]*muW[j*128 + k];
    sl += hrow[k]*lvW[j*128 + k];
  }
  float mu = fmaxf(sm, 0.1f*sm);
  float lv = fmaxf(sl, 0.1f*sl);
  lv = fminf(fmaxf(lv, -10.0f), 10.0f);
  float em = mu + eps[b*64 + j]*__expf(0.5f*lv);
  emb[j] = em;
  out[115200 + b*64 + j] = mu;
  out[123392 + b*64 + j] = lv;
  __syncthreads();
  for (int c4 = 0; c4 < 4; ++c4) {
    int c = c4*64 + j;
    float s = fcb[c];
    for (int k = 0; k < 64; ++k) s += emb[k]*fcW[c*64 + k];
    xvec[b*256 + c] = s;
  }
}

// ---------------------------------------------------------------------------
// pv_gxbase: unchanged.
// ---------------------------------------------------------------------------
__global__ __launch_bounds__(256) void pv_gxbase(
    const float* xvec, const float* Wih,
    const float* bih, const float* bhh, float* gxb)
{
  __shared__ float xs[8*256];
  const int tid = threadIdx.x;
  const int bg = blockIdx.x;
  const int gg = blockIdx.y;
  for (int i = tid; i < 2048; i += 256) xs[i] = xvec[bg*2048 + i];
  __syncthreads();
  const int g = gg*256 + tid;
  if (g >= 783) return;
  float bias = bih[g] + ((g < 522) ? bhh[g] : 0.0f);
  float a0=bias,a1=bias,a2=bias,a3=bias,a4=bias,a5=bias,a6=bias,a7=bias;
  const float* wr = Wih + g*261;
  for (int k = 0; k < 256; ++k) {
    float w = wr[k];
    a0 += xs[0*256 + k]*w; a1 += xs[1*256 + k]*w;
    a2 += xs[2*256 + k]*w; a3 += xs[3*256 + k]*w;
    a4 += xs[4*256 + k]*w; a5 += xs[5*256 + k]*w;
    a6 += xs[6*256 + k]*w; a7 += xs[7*256 + k]*w;
  }
  gxb[(bg*8 + 0)*783 + g] = a0; gxb[(bg*8 + 1)*783 + g] = a1;
  gxb[(bg*8 + 2)*783 + g] = a2; gxb[(bg*8 + 3)*783 + g] = a3;
  gxb[(bg*8 + 4)*783 + g] = a4; gxb[(bg*8 + 5)*783 + g] = a5;
  gxb[(bg*8 + 6)*783 + g] = a6; gxb[(bg*8 + 7)*783 + g] = a7;
}

// ---------------------------------------------------------------------------
// pv_gru: 8 WGs x 1024 threads, 16 batches/WG.  Whh as fp8 e4m3 MFMA
// B-fragments RESIDENT IN VGPRS (x8 scale); launch_bounds(1024,4) -> 128-VGPR
// cap so bfr (72 VGPRs) stays in registers.  h/noise/time in A (x4 scale);
// D /= 32.  Writes hseq fp32 [t][b][261].
// ---------------------------------------------------------------------------
__global__ __launch_bounds__(1024, 4) void pv_gru(
    const float* gxb, const unsigned long long* wfp8, const float* Wih,
    const float* bhh, const float* noise, float* hseq)
{
  __shared__ __align__(16) unsigned char Afp8[16*296];  // A fp8, row stride 296
  __shared__ float Ds[16*788];                          // D, row stride 788
  __shared__ float WihN[261*5];                         // n-gate noise/time weights
  __shared__ float bhhN[261];

  const int tid = threadIdx.x;
  const int wv = tid >> 6;
  const int lane = tid & 63;
  const int l16 = lane & 15, quad = lane >> 4;
  const int m0 = blockIdx.x * 16;
  const int tbase = (wv < 15) ? wv*3 : 45;
  const int ntiles = (wv < 15) ? 3 : 4;     // 49 tiles of 16 over 784 gates

  long bfr[4][9];
  #pragma unroll
  for (int tt = 0; tt < 4; ++tt) {
    if (tt < ntiles) {
      #pragma unroll
      for (int c = 0; c < 9; ++c)
        bfr[tt][c] = (long)wfp8[((tbase + tt)*9 + c)*64 + lane];
    } else {
      #pragma unroll
      for (int c = 0; c < 9; ++c) bfr[tt][c] = 0;
    }
  }
  for (int i = tid; i < 261*5; i += 1024) WihN[i] = Wih[(522 + i/5)*261 + 256 + (i % 5)];
  for (int i = tid; i < 261; i += 1024) bhhN[i] = bhh[522 + i];
  for (int i = tid; i < 16*296; i += 1024) Afp8[i] = 0;
  __syncthreads();
  if (tid < 80) {   // A noise/time columns for t=0 (time_0 = 0)
    const int m = tid/5, i = tid - (tid/5)*5;
    float v = (i < 4) ? noise[(m0 + m)*4 + i]*0.1f : 0.0f;
    Afp8[m*296 + 261 + i] = pv_fp8(4.0f*v);
  }
  float hreg[5] = {0,0,0,0,0};
  __syncthreads();

  for (int t = 0; t < 100; ++t) {
    f32x4 acc[4];
    #pragma unroll
    for (int tt = 0; tt < 4; ++tt) acc[tt] = (f32x4){0,0,0,0};
    #pragma unroll
    for (int c = 0; c < 9; ++c) {
      const long a = *(const long*)(Afp8 + l16*296 + c*32 + quad*8);
      #pragma unroll
      for (int tt = 0; tt < 4; ++tt)
        if (tt < ntiles)
          acc[tt] = __builtin_amdgcn_mfma_f32_16x16x32_fp8_fp8(a, bfr[tt][c], acc[tt], 0, 0, 0);
    }
    #pragma unroll
    for (int tt = 0; tt < 4; ++tt)
      if (tt < ntiles) {
        const int n = (tbase + tt)*16 + l16;
        #pragma unroll
        for (int r = 0; r < 4; ++r)
          Ds[(quad*4 + r)*788 + n] = acc[tt][r];
      }
    __syncthreads();
    const float inv32 = 1.0f/32.0f;
    const float tv = (float)t * (1.0f/99.0f);
    #pragma unroll
    for (int e = 0; e < 5; ++e) {
      const int el = tid + e*1024;
      if (el < 4176) {
        const int m = el/261, j = el - (el/261)*261;
        const float* dr = Ds + m*788;
        float Dr = dr[j]*inv32, Dz = dr[261 + j]*inv32, Dn = dr[522 + j]*inv32;
        const float* gb = gxb + (m0 + m)*783;
        const float* wn = WihN + j*5;
        const float* ne = noise + (t*128 + m0 + m)*4;
        float gn = gb[522 + j]
                 + 0.1f*(ne[0]*wn[0] + ne[1]*wn[1] + ne[2]*wn[2] + ne[3]*wn[3])
                 + tv*wn[4];
        float r_ = pv_sigm(Dr + gb[j]);
        float z_ = pv_sigm(Dz + gb[261 + j]);
        float n_ = pv_tanh(gn + r_*(Dn + bhhN[j]));
        float h = (1.0f - z_)*n_ + z_*hreg[e];
        hreg[e] = h;
        hseq[(t*128 + m0 + m)*261 + j] = h;
        Afp8[m*296 + j] = pv_fp8(4.0f*h);
      }
    }
    if (tid < 80 && t < 99) {   // A noise/time for t+1
      const int m = tid/5, i = tid - (tid/5)*5;
      float v = (i < 4) ? noise[((t+1)*128 + m0 + m)*4 + i]*0.1f
                        : (t+1)*(1.0f/99.0f);
      Afp8[m*296 + 261 + i] = pv_fp8(4.0f*v);
    }
    __syncthreads();
  }
}

// ---------------------------------------------------------------------------
// pv_frames: unchanged.
// ---------------------------------------------------------------------------
__global__ __launch_bounds__(256) void pv_frames(
    const float* hseq, const float* W1, const float* b1,
    const float* W2, const float* b2, float* out)
{
  __shared__ __align__(16) float h16[16*264];
  __shared__ unsigned w1p[64*133];
  __shared__ float f1s[16*66];
  __shared__ float w2s[576];
  const int tid = threadIdx.x;
  const int r0 = blockIdx.x * 16;    // rows rt = t*128 + b
  for (int i = tid; i < 16*264; i += 256) {
    int r = i / 264, k = i - r*264;
    h16[i] = (k < 261) ? hseq[(r0 + r)*261 + k] : 0.0f;
  }
  for (int i = tid; i < 64*131; i += 256) {
    int c = i/131, kp = i - (i/131)*131;
    int k = kp*2;
    float a0 = W1[c*261 + k];
    float a1 = (k + 1 < 261) ? W1[c*261 + k + 1] : 0.0f;
    w1p[c*133 + kp] = pv_pack2(a0, a1);
  }
  for (int i = tid; i < 576; i += 256) w2s[i] = W2[i];
  __syncthreads();
  #pragma unroll
  for (int e = 0; e < 4; ++e) {
    const int el = tid + e*256;
    const int r = el >> 6, c = el & 63;
    float s = b1[c];
    const unsigned* wp = w1p + c*133;
    const float* hr = h16 + r*264;
    for (int kp = 0; kp < 131; ++kp) {
      unsigned w = wp[kp];
      s += pv_lo(w)*hr[2*kp] + pv_hi(w)*hr[2*kp + 1];
    }
    f1s[r*66 + c] = fmaxf(s, 0.2f*s);
  }
  __syncthreads();
  if (tid < 144) {
    const int r = tid/9, oc = tid - (tid/9)*9;
    float s = b2[oc];
    const float* fr = f1s + r*66;
    const float* w = w2s + oc*64;
    #pragma unroll 8
    for (int k = 0; k < 64; ++k) s += fr[k]*w[k];
    const int rt = r0 + r;
    const int tt = rt >> 7, bb = rt & 127;
    out[bb*900 + tt*9 + oc] = pv_sigm(s);
  }
}

// ---------------------------------------------------------------------------
extern "C" __attribute__((visibility("default")))
void kernel_launch(void* const* d_in, const int* in_sizes, int n_in,
                   void* d_out, int out_size, void* d_ws, size_t ws_size,
                   hipStream_t stream)
{
  (void)in_sizes; (void)n_in; (void)out_size; (void)ws_size;
  const float* input_data = (const float*)d_in[0];
  const float* eps        = (const float*)d_in[1];
  const float* noise_eps  = (const float*)d_in[2];
  const float* proj_W     = (const float*)d_in[3];
  const float* proj_b     = (const float*)d_in[4];
  const float* lstm_Wih   = (const float*)d_in[5];
  const float* lstm_Whh   = (const float*)d_in[6];
  const float* lstm_bih   = (const float*)d_in[7];
  const float* lstm_bhh   = (const float*)d_in[8];
  const float* mu_W       = (const float*)d_in[9];
  const float* mu_b       = (const float*)d_in[10];
  const float* lv_W       = (const float*)d_in[11];
  const float* lv_b       = (const float*)d_in[12];
  const float* fcin_W     = (const float*)d_in[13];
  const float* fcin_b     = (const float*)d_in[14];
  const float* gru_Wih    = (const float*)d_in[15];
  const float* gru_Whh    = (const float*)d_in[16];
  const float* gru_bih    = (const float*)d_in[17];
  const float* gru_bhh    = (const float*)d_in[18];
  const float* jf_W1      = (const float*)d_in[19];
  const float* jf_b1      = (const float*)d_in[20];
  const float* jf_W2      = (const float*)d_in[21];
  const float* jf_b2      = (const float*)d_in[22];

  char* w = (char*)d_ws;
  float*              xg   = (float*)(w);                          // 26,214,400 B
  unsigned long long* wfp8 = (unsigned long long*)(w + 26214400);  //    225,792 B
  float*              hT   = (float*)(w + 26440192);               //     65,536 B
  float*              xvec = (float*)(w + 26505728);               //    131,072 B
  float*              gxb  = (float*)(w + 26636800);               //    400,896 B
  float*              hseq = (float*)(w + 27037696);               // 13,363,200 B (end 40.4 MB)
  float*              outf = (float*)d_out;

  pv_prep_gru8<<<111, 256, 0, stream>>>(gru_Whh, gru_Wih, wfp8);
  pv_gemm<<<dim3(100, 4), 256, 0, stream>>>(input_data, proj_W, proj_b,
                                            lstm_Wih, lstm_bih, lstm_bhh, xg);
  pv_lstm<<<8, 1024, 0, stream>>>(xg, lstm_Whh, hT);
  pv_head<<<128, 64, 0, stream>>>(hT, eps, mu_W, mu_b, lv_W, lv_b,
                                  fcin_W, fcin_b, xvec, outf);
  pv_gxbase<<<dim3(16, 4), 256, 0, stream>>>(xvec, gru_Wih, gru_bih, gru_bhh, gxb);
  pv_gru<<<8, 1024, 0, stream>>>(gxb, wfp8, gru_Wih, gru_bhh, noise_eps, hseq);
  pv_frames<<<800, 256, 0, stream>>>(hseq, jf_W1, jf_b1, jf_W2, jf_b2, outf);
}